// Round 1
// baseline (46.742 us; speedup 1.0000x reference)
//
#include <hip/hip_runtime.h>

#define DIM 256
#define BATCH 16384
#define MARGIN 1.0f
#define EPSV 1e-6f

__device__ __forceinline__ float waveReduceSum(float v) {
#pragma unroll
    for (int m = 32; m > 0; m >>= 1) v += __shfl_xor(v, m, 64);
    return v;
}

// Computes the TransD score for triple i of `tri`. One full wave cooperates;
// lane l owns elements [4l, 4l+4) of the 256-dim embedding row.
__device__ __forceinline__ float score_one(const int* __restrict__ tri, int i,
                                           const float* __restrict__ ent,
                                           const float* __restrict__ entm,
                                           const float* __restrict__ rel,
                                           const float* __restrict__ relm,
                                           int lane) {
    const int h_idx = tri[i * 3 + 0];
    const int r_idx = tri[i * 3 + 1];
    const int t_idx = tri[i * 3 + 2];

    const float4* hrow  = (const float4*)(ent  + (size_t)h_idx * DIM);
    const float4* hprow = (const float4*)(entm + (size_t)h_idx * DIM);
    const float4* trow  = (const float4*)(ent  + (size_t)t_idx * DIM);
    const float4* tprow = (const float4*)(entm + (size_t)t_idx * DIM);
    const float4* rrow  = (const float4*)(rel  + (size_t)r_idx * DIM);
    const float4* rprow = (const float4*)(relm + (size_t)r_idx * DIM);

    // Issue all six 16B/lane loads up-front so they overlap.
    float4 hv  = hrow[lane];
    float4 hpv = hprow[lane];
    float4 tv  = trow[lane];
    float4 tpv = tprow[lane];
    float4 rv  = rrow[lane];
    float4 rpv = rprow[lane];

    float alpha = waveReduceSum(hv.x * hpv.x + hv.y * hpv.y + hv.z * hpv.z + hv.w * hpv.w);
    float beta  = waveReduceSum(tv.x * tpv.x + tv.y * tpv.y + tv.z * tpv.z + tv.w * tpv.w);

    // h_proj - t_proj = rp*(alpha-beta) + h - t ; diff = that + r + EPS (per element)
    const float ab = alpha - beta;
    float dx = rpv.x * ab + hv.x + rv.x - tv.x + EPSV;
    float dy = rpv.y * ab + hv.y + rv.y - tv.y + EPSV;
    float dz = rpv.z * ab + hv.z + rv.z - tv.z + EPSV;
    float dw = rpv.w * ab + hv.w + rv.w - tv.w + EPSV;

    float ss = waveReduceSum(dx * dx + dy * dy + dz * dz + dw * dw);
    return sqrtf(ss);
}

// 4 waves per block; wave w of block b handles triple (b*4 + w).
__global__ __launch_bounds__(256) void transd_loss_kernel(
    const int* __restrict__ pos_x, const int* __restrict__ neg_x,
    const float* __restrict__ ent, const float* __restrict__ entm,
    const float* __restrict__ rel, const float* __restrict__ relm,
    float* __restrict__ partial) {
    const int wave = (blockIdx.x * blockDim.x + threadIdx.x) >> 6;
    const int lane = threadIdx.x & 63;
    if (wave >= BATCH) return;

    float pos_s = score_one(pos_x, wave, ent, entm, rel, relm, lane);
    float neg_s = score_one(neg_x, wave, ent, entm, rel, relm, lane);

    if (lane == 0) {
        float v = pos_s - neg_s + MARGIN;
        partial[wave] = v > 0.0f ? v : 0.0f;
    }
}

// Deterministic single-block reduction of BATCH floats -> out[0] = sum / BATCH.
__global__ __launch_bounds__(256) void reduce_kernel(const float* __restrict__ partial,
                                                     float* __restrict__ out) {
    __shared__ float smem[256];
    float s = 0.0f;
    for (int i = threadIdx.x; i < BATCH; i += 256) s += partial[i];
    smem[threadIdx.x] = s;
    __syncthreads();
#pragma unroll
    for (int step = 128; step > 0; step >>= 1) {
        if (threadIdx.x < step) smem[threadIdx.x] += smem[threadIdx.x + step];
        __syncthreads();
    }
    if (threadIdx.x == 0) out[0] = smem[0] / (float)BATCH;
}

extern "C" void kernel_launch(void* const* d_in, const int* in_sizes, int n_in,
                              void* d_out, int out_size, void* d_ws, size_t ws_size,
                              hipStream_t stream) {
    const int*   pos_x = (const int*)d_in[0];
    const int*   neg_x = (const int*)d_in[1];
    const float* ent   = (const float*)d_in[2];
    const float* entm  = (const float*)d_in[3];
    const float* rel   = (const float*)d_in[4];
    const float* relm  = (const float*)d_in[5];

    float* partial = (float*)d_ws;  // BATCH floats = 64 KB
    float* out     = (float*)d_out;

    // 4 waves (triples) per 256-thread block -> BATCH/4 blocks.
    const int blocks = BATCH / 4;
    transd_loss_kernel<<<blocks, 256, 0, stream>>>(pos_x, neg_x, ent, entm, rel, relm, partial);
    reduce_kernel<<<1, 256, 0, stream>>>(partial, out);
}

// Round 2
// 35.342 us; speedup vs baseline: 1.3226x; 1.3226x over previous
//
#include <hip/hip_runtime.h>

#define DIM 256
#define BATCH 16384
#define MARGIN 1.0f
#define EPSV 1e-6f

#define NBLOCKS (BATCH / 4)  // 4 waves per 256-thread block, 1 triple-pair per wave

__device__ __forceinline__ float dot4(float4 a, float4 b) {
    return a.x * b.x + a.y * b.y + a.z * b.z + a.w * b.w;
}

// One wave per (pos,neg) triple pair. Lane l owns elements [4l,4l+4) of DIM=256.
__global__ __launch_bounds__(256) void transd_loss_kernel(
    const int* __restrict__ pos_x, const int* __restrict__ neg_x,
    const float* __restrict__ ent, const float* __restrict__ entm,
    const float* __restrict__ rel, const float* __restrict__ relm,
    float* __restrict__ partial) {
    const int wave = (blockIdx.x * blockDim.x + threadIdx.x) >> 6;
    const int lane = threadIdx.x & 63;

    // --- all 6 indices up-front (one latency) ---
    const int ph = pos_x[wave * 3 + 0];
    const int pr = pos_x[wave * 3 + 1];
    const int pt = pos_x[wave * 3 + 2];
    const int nh = neg_x[wave * 3 + 0];
    const int nr = neg_x[wave * 3 + 1];
    const int nt = neg_x[wave * 3 + 2];

    // --- all 12 row loads up-front (12 outstanding 1KB vector loads) ---
    const float4* p_h  = (const float4*)(ent  + (size_t)ph * DIM);
    const float4* p_hp = (const float4*)(entm + (size_t)ph * DIM);
    const float4* p_t  = (const float4*)(ent  + (size_t)pt * DIM);
    const float4* p_tp = (const float4*)(entm + (size_t)pt * DIM);
    const float4* p_r  = (const float4*)(rel  + (size_t)pr * DIM);
    const float4* p_rp = (const float4*)(relm + (size_t)pr * DIM);
    const float4* n_h  = (const float4*)(ent  + (size_t)nh * DIM);
    const float4* n_hp = (const float4*)(entm + (size_t)nh * DIM);
    const float4* n_t  = (const float4*)(ent  + (size_t)nt * DIM);
    const float4* n_tp = (const float4*)(entm + (size_t)nt * DIM);
    const float4* n_r  = (const float4*)(rel  + (size_t)nr * DIM);
    const float4* n_rp = (const float4*)(relm + (size_t)nr * DIM);

    float4 phv  = p_h[lane];
    float4 phpv = p_hp[lane];
    float4 ptv  = p_t[lane];
    float4 ptpv = p_tp[lane];
    float4 prv  = p_r[lane];
    float4 prpv = p_rp[lane];
    float4 nhv  = n_h[lane];
    float4 nhpv = n_hp[lane];
    float4 ntv  = n_t[lane];
    float4 ntpv = n_tp[lane];
    float4 nrv  = n_r[lane];
    float4 nrpv = n_rp[lane];

    // --- 4 dot-product partials, reduced with interleaved (pipelined) shfl chains ---
    float ap = dot4(phv, phpv);
    float bp = dot4(ptv, ptpv);
    float an = dot4(nhv, nhpv);
    float bn = dot4(ntv, ntpv);
#pragma unroll
    for (int m = 32; m > 0; m >>= 1) {
        ap += __shfl_xor(ap, m, 64);
        bp += __shfl_xor(bp, m, 64);
        an += __shfl_xor(an, m, 64);
        bn += __shfl_xor(bn, m, 64);
    }
    const float abp = ap - bp;  // pos: alpha - beta
    const float abn = an - bn;  // neg: alpha - beta

    // diff = rp*(alpha-beta) + h + r - t + EPS  (per element)
    float dpx = prpv.x * abp + phv.x + prv.x - ptv.x + EPSV;
    float dpy = prpv.y * abp + phv.y + prv.y - ptv.y + EPSV;
    float dpz = prpv.z * abp + phv.z + prv.z - ptv.z + EPSV;
    float dpw = prpv.w * abp + phv.w + prv.w - ptv.w + EPSV;
    float dnx = nrpv.x * abn + nhv.x + nrv.x - ntv.x + EPSV;
    float dny = nrpv.y * abn + nhv.y + nrv.y - ntv.y + EPSV;
    float dnz = nrpv.z * abn + nhv.z + nrv.z - ntv.z + EPSV;
    float dnw = nrpv.w * abn + nhv.w + nrv.w - ntv.w + EPSV;

    float ssp = dpx * dpx + dpy * dpy + dpz * dpz + dpw * dpw;
    float ssn = dnx * dnx + dny * dny + dnz * dnz + dnw * dnw;
#pragma unroll
    for (int m = 32; m > 0; m >>= 1) {
        ssp += __shfl_xor(ssp, m, 64);
        ssn += __shfl_xor(ssn, m, 64);
    }

    // --- block-level sum: 4 waves -> 1 float ---
    __shared__ float smem[4];
    if (lane == 0) {
        float v = sqrtf(ssp) - sqrtf(ssn) + MARGIN;
        smem[threadIdx.x >> 6] = v > 0.0f ? v : 0.0f;
    }
    __syncthreads();
    if (threadIdx.x == 0)
        partial[blockIdx.x] = (smem[0] + smem[1]) + (smem[2] + smem[3]);
}

// Deterministic single-block reduction of NBLOCKS floats -> out[0] = sum / BATCH.
__global__ __launch_bounds__(256) void reduce_kernel(const float* __restrict__ partial,
                                                     float* __restrict__ out) {
    const int lane = threadIdx.x & 63;
    float s = 0.0f;
#pragma unroll
    for (int i = threadIdx.x; i < NBLOCKS; i += 256) s += partial[i];
#pragma unroll
    for (int m = 32; m > 0; m >>= 1) s += __shfl_xor(s, m, 64);
    __shared__ float smem[4];
    if (lane == 0) smem[threadIdx.x >> 6] = s;
    __syncthreads();
    if (threadIdx.x == 0)
        out[0] = ((smem[0] + smem[1]) + (smem[2] + smem[3])) / (float)BATCH;
}

extern "C" void kernel_launch(void* const* d_in, const int* in_sizes, int n_in,
                              void* d_out, int out_size, void* d_ws, size_t ws_size,
                              hipStream_t stream) {
    const int*   pos_x = (const int*)d_in[0];
    const int*   neg_x = (const int*)d_in[1];
    const float* ent   = (const float*)d_in[2];
    const float* entm  = (const float*)d_in[3];
    const float* rel   = (const float*)d_in[4];
    const float* relm  = (const float*)d_in[5];

    float* partial = (float*)d_ws;  // NBLOCKS floats = 16 KB
    float* out     = (float*)d_out;

    transd_loss_kernel<<<NBLOCKS, 256, 0, stream>>>(pos_x, neg_x, ent, entm, rel, relm, partial);
    reduce_kernel<<<1, 256, 0, stream>>>(partial, out);
}